// Round 11
// baseline (551.249 us; speedup 1.0000x reference)
//
#include <hip/hip_runtime.h>
#include <math.h>

// ---------------- problem constants ----------------
constexpr int Bn  = 2;
constexpr int HWn = 4096;     // H*W
constexpr int Nn  = 4096;
constexpr int KQn = 32;
constexpr int KNn = 16;
constexpr float INV_R1 = 1.0f/262144.0f;   // exact pow2
constexpr float INV_R2 = 1.0f/131072.0f;   // exact pow2

typedef _Float16 f16x8 __attribute__((ext_vector_type(8)));
typedef float    f32x4 __attribute__((ext_vector_type(4)));

__device__ __forceinline__ float wred64(float v){
  #pragma unroll
  for (int m = 32; m > 0; m >>= 1) v += __shfl_xor(v, m, 64);
  return v;
}
__device__ __forceinline__ float leakyf(float v){ return v > 0.f ? v : 0.1f*v; }

__device__ __forceinline__ void bn_param(const float* st, int c, float inv_n,
                                         const float* g, const float* e,
                                         float& sc, float& sh){
  float mu  = st[c]*inv_n;
  float var = st[128+c]*inv_n - mu*mu;
  float s   = g[c]*rsqrtf(var + 1e-5f);
  sc = s; sh = e[c] - mu*s;
}

// Build the 70-channel stage-1 input row: [wxyz(3), f2_xyz[idx](3), normW*normF2(64)]
__device__ __forceinline__ void build_x70(int row,
    const float* __restrict__ wxyz, const float* __restrict__ f2_xyz,
    const float* __restrict__ normW, const float* __restrict__ normF2,
    const int* __restrict__ idxq, float* x){
  int p = row >> 5;
  int b = p >> 12;
  int idx = idxq[row];
  const float* wx = wxyz + (size_t)p*3;
  const float* fx = f2_xyz + ((size_t)b*Nn + idx)*3;
  x[0]=wx[0]; x[1]=wx[1]; x[2]=wx[2];
  x[3]=fx[0]; x[4]=fx[1]; x[5]=fx[2];
  const float4* nw = (const float4*)(normW  + (size_t)p*64);
  const float4* nf = (const float4*)(normF2 + ((size_t)b*Nn + idx)*64);
  #pragma unroll
  for (int c=0;c<16;c++){
    float4 a = nw[c], q = nf[c];
    x[6+4*c+0]=a.x*q.x; x[6+4*c+1]=a.y*q.y; x[6+4*c+2]=a.z*q.z; x[6+4*c+3]=a.w*q.w;
  }
}

// Build the 10-channel stage-2 geometry row
__device__ __forceinline__ void build_x10(int row,
    const float* __restrict__ wxyz, const int* __restrict__ idx2, float* x){
  int p = row >> 4, b = p >> 12;
  int idx = idx2[row];
  const float* nw = wxyz + (size_t)p*3;
  const float* gw = wxyz + ((size_t)b*HWn + idx)*3;
  float n0=nw[0],n1=nw[1],n2=nw[2];
  float g0=gw[0],g1=gw[1],g2=gw[2];
  float d0=g0-n0, d1=g1-n1, d2=g2-n2;
  x[0]=n0;x[1]=n1;x[2]=n2; x[3]=g0;x[4]=g1;x[5]=g2;
  x[6]=d0;x[7]=d1;x[8]=d2; x[9]=sqrtf(d0*d0+d1*d1+d2*d2+1e-20f);
}

// padded LDS index for the 4096-bin histogram (kills stride-16 scan conflicts)
__device__ __forceinline__ int hidx(int d){ return d + (d >> 4); }

// ---------------- prep: norms, wxyz, weight transposes + f16 weights ----------------
__global__ __launch_bounds__(256) void k_prep(
    const float* __restrict__ warped_xyz, const float* __restrict__ lidar_z,
    const float* __restrict__ warped_points, const float* __restrict__ f2_points,
    const float* __restrict__ m1w0, const float* __restrict__ m1w1,
    const float* __restrict__ piw, const float* __restrict__ pcw,
    const float* __restrict__ m2w0, const float* __restrict__ m2w1,
    const float* __restrict__ m3w0, const float* __restrict__ m3w1,
    float* __restrict__ wxyz, float* __restrict__ normW, float* __restrict__ normF2,
    float* __restrict__ piwT, float* __restrict__ pcwT,
    _Float16* __restrict__ w1h, _Float16* __restrict__ w2h,
    _Float16* __restrict__ w3h, _Float16* __restrict__ w4h,
    _Float16* __restrict__ w5h, _Float16* __restrict__ w6h)
{
  int blk = blockIdx.x, tid = threadIdx.x;
  if (blk < 4096){
    int lane = tid & 63;
    int p = blk*4 + (tid >> 6);            // 0..16383
    const float* src; float* dst;
    if (p < Bn*HWn){ src = warped_points + (size_t)p*64; dst = normW + (size_t)p*64; }
    else { int q = p - Bn*HWn; src = f2_points + (size_t)q*64; dst = normF2 + (size_t)q*64; }
    float x = src[lane];
    float m = wred64(x) * (1.f/64.f);
    float d = x - m;
    float ss = wred64(d*d);
    float s = fmaxf(sqrtf(ss*(1.f/63.f)), 1e-12f);
    dst[lane] = d / s;
  } else if (blk < 4192){
    int e = (blk-4096)*256 + tid;          // < 24576
    wxyz[e] = warped_xyz[e] * lidar_z[e/3];
  } else if (blk < 4196){
    int e = (blk-4192)*256 + tid;          // < 1024
    if (e < 384){ piwT[(e & 63)*6  + (e >> 6)] = piw[e]; }
    else if (e < 1024){ int f = e-384; pcwT[(f & 63)*10 + (f >> 6)] = pcw[f]; }
  } else {
    int e = (blk-4196)*256 + tid;          // < 49152
    if (e < 12288){                        // w1h[j][k] : [128 out][96 in-pad]
      int j = e/96, k = e - j*96;
      w1h[e] = (k < 70) ? (_Float16)m1w0[k*128 + j] : (_Float16)0.f;
    } else if (e < 20480){                 // w2h[d][c] : [64][128]
      int f = e - 12288; int d = f >> 7, c = f & 127;
      w2h[f] = (_Float16)m1w1[c*64 + d];
    } else if (e < 28672){                 // w3h[d][c] : [64][128]
      int f = e - 20480; int d = f >> 7, c = f & 127;
      w3h[f] = (_Float16)m2w0[c*64 + d];
    } else if (e < 32768){                 // w4h[d][c] : [64][64]
      int f = e - 28672; int d = f >> 6, c = f & 63;
      w4h[f] = (_Float16)m2w1[c*64 + d];
    } else if (e < 45056){                 // w5h[d][c] : [64][192]
      int f = e - 32768; int d = f/192, c = f - 192*d;
      w5h[f] = (_Float16)m3w0[c*64 + d];
    } else {                               // w6h[d][c] : [64][64]
      int f = e - 45056; int d = f >> 6, c = f & 63;
      w6h[f] = (_Float16)m3w1[c*64 + d];
    }
  }
}

// ---------------- exact k-smallest: 12-bit first-digit radix select ----------------
// Pass 1: 4096 padded bins over informative bits [L-11, L] of (key - blockmin);
// expected bucket ~1 => early exit. Fallback 8-bit passes for residual ties.
// Blocks 0..8191 = KQ(32), 8192..16383 = KN(16)+valid.
__global__ __launch_bounds__(256) void k_knn_all(
    const float* __restrict__ qA, const float* __restrict__ pA, int* __restrict__ oA,
    const float* __restrict__ qB, const float* __restrict__ pB, int* __restrict__ oB,
    float* __restrict__ ovalid)
{
  __shared__ int hist[4352];                 // 4096 bins, padded d+(d>>4)
  __shared__ int wsum[4];
  __shared__ unsigned int redm[4], redM[4];
  __shared__ int sh_sel, sh_rem, sh_cls, cnt_lt, cnt_eq;
  bool second = blockIdx.x >= 8192;
  int blk = second ? (blockIdx.x - 8192) : blockIdx.x;
  int K = second ? KNn : KQn;
  const float* qpts = second ? qB : qA;
  const float* pts  = second ? pB : pA;
  int* oidx = second ? oB : oA;
  int b = blk >> 12;
  int qi = blk & 4095;
  int tid = threadIdx.x;
  int lane = tid & 63, wv = tid >> 6;
  const float* qp = qpts + ((size_t)(b*HWn+qi))*3;
  float qx=qp[0], qy=qp[1], qz=qp[2];
  const float* pb = pts + (size_t)b*Nn*3;
  unsigned int key[16];
  {
    const float4* pb4 = (const float4*)(pb + (size_t)tid*48);  // 16 pts = 48 floats
    float4 v[12];
    #pragma unroll
    for (int i=0;i<12;i++) v[i] = pb4[i];
    const float* f = (const float*)v;
    #pragma unroll
    for (int i=0;i<16;i++){
      float dx = __fsub_rn(qx, f[i*3+0]);
      float dy = __fsub_rn(qy, f[i*3+1]);
      float dz = __fsub_rn(qz, f[i*3+2]);
      float d2 = __fadd_rn(__fadd_rn(__fmul_rn(dx,dx), __fmul_rn(dy,dy)), __fmul_rn(dz,dz));
      key[i] = __float_as_uint(d2);        // nonneg floats: uint order == float order
    }
  }
  // block min/max of keys
  unsigned int mn = key[0], mx = key[0];
  #pragma unroll
  for (int i=1;i<16;i++){ mn = min(mn, key[i]); mx = max(mx, key[i]); }
  #pragma unroll
  for (int m=32;m>0;m>>=1){
    mn = min(mn, (unsigned int)__shfl_xor((int)mn, m, 64));
    mx = max(mx, (unsigned int)__shfl_xor((int)mx, m, 64));
  }
  if (lane == 0){ redm[wv] = mn; redM[wv] = mx; }
  if (tid == 0){ cnt_lt = 0; cnt_eq = 0; }
  __syncthreads();
  mn = min(min(redm[0],redm[1]), min(redm[2],redm[3]));
  mx = max(max(redM[0],redM[1]), max(redM[2],redM[3]));
  unsigned int R = mx - mn;
  int L = (R == 0u) ? 0 : (31 - __clz(R));
  int shift = (L > 11) ? (L - 11) : 0;
  unsigned int dmask = 4095u;

  unsigned int active = 0xFFFFu, below = 0u;
  int rem = K;
  bool first = true;
  for (;;){
    __syncthreads();                       // guard hist reuse
    if (first){
      for (int i=tid; i<4352; i+=256) hist[i] = 0;
    } else {
      hist[hidx(tid)] = 0;
    }
    __syncthreads();
    #pragma unroll
    for (int i=0;i<16;i++){
      if (active & (1u<<i))
        atomicAdd(&hist[hidx((int)(((key[i]-mn) >> shift) & dmask))], 1);
    }
    __syncthreads();
    if (first){
      // hierarchical scan over 4096 bins: 16/thread, padded reads (17-stride)
      int base = tid*17;                   // == hidx(tid*16)
      int hv[16]; int tot = 0;
      #pragma unroll
      for (int i=0;i<16;i++){ hv[i] = hist[base+i]; tot += hv[i]; }
      int pref = tot;
      #pragma unroll
      for (int m=1;m<64;m<<=1){ int t = __shfl_up(pref, m, 64); if (lane >= m) pref += t; }
      if (lane == 63) wsum[wv] = pref;
      __syncthreads();
      int off = 0;
      #pragma unroll
      for (int i=0;i<3;i++) if (i < wv) off += wsum[i];
      pref += off;                         // inclusive prefix of thread totals
      if (pref >= rem && (pref - tot) < rem){
        int running = pref - tot;
        bool done = false;
        #pragma unroll
        for (int i=0;i<16;i++){
          if (!done && running + hv[i] >= rem){
            sh_sel = tid*16 + i;
            sh_rem = rem - running;
            sh_cls = hv[i];
            done = true;
          }
          if (!done) running += hv[i];
        }
      }
    } else {
      int h = hist[hidx(tid)];
      int pref = h;
      #pragma unroll
      for (int m=1;m<64;m<<=1){ int t = __shfl_up(pref, m, 64); if (lane >= m) pref += t; }
      if (lane == 63) wsum[wv] = pref;
      __syncthreads();
      int off = 0;
      #pragma unroll
      for (int i=0;i<3;i++) if (i < wv) off += wsum[i];
      pref += off;
      if (pref >= rem && (pref - h) < rem){
        sh_sel = tid;
        sh_rem = rem - (pref - h);
        sh_cls = h;
      }
    }
    __syncthreads();
    unsigned int sel = (unsigned int)sh_sel; rem = sh_rem; int cls = sh_cls;
    #pragma unroll
    for (int i=0;i<16;i++){
      if (active & (1u<<i)){
        unsigned int d = ((key[i]-mn) >> shift) & dmask;
        if (d < sel) below |= (1u<<i);
        if (d != sel) active &= ~(1u<<i);
      }
    }
    if (cls == rem || shift == 0) break;
    int w = (shift < 8) ? shift : 8;
    shift -= w;
    dmask = (w == 8) ? 255u : ((1u<<w) - 1u);
    first = false;
  }
  // output: all 'below' + rem of the final equal-class
  size_t obase = ((size_t)(b*HWn+qi))*K;
  int nless = K - rem;
  const unsigned int U100 = __float_as_uint(100.0f);  // DIST*DIST
  #pragma unroll
  for (int i=0;i<16;i++){
    if (below & (1u<<i)){
      int s = atomicAdd(&cnt_lt, 1);
      oidx[obase+s] = tid*16 + i;
      if (second) ovalid[obase+s] = (key[i] < U100) ? 1.f : 0.f;
    } else if (active & (1u<<i)){
      int s = atomicAdd(&cnt_eq, 1);
      if (s < rem){
        oidx[obase+nless+s] = tid*16 + i;
        if (second) ovalid[obase+nless+s] = (key[i] < U100) ? 1.f : 0.f;
      }
    }
  }
}

// ---------------- fused: build X1 rows + y1 stats MFMA + Gram matrices ----------------
__global__ __launch_bounds__(256) void k_build_stats(
    const float* __restrict__ wxyz, const float* __restrict__ f2_xyz,
    const float* __restrict__ normW, const float* __restrict__ normF2,
    const int* __restrict__ idxq, const int* __restrict__ idx2,
    const _Float16* __restrict__ w1h,
    _Float16* __restrict__ X1, float* stats, float* __restrict__ gram)
{
  __shared__ float ssum[128], sssq[128];
  __shared__ float sacc[66];
  int blk = blockIdx.x, tid = threadIdx.x, lane = tid & 63;
  if (blk < 1024){
    int row = blk*256 + tid;
    {
      float x[70];
      build_x70(row, wxyz, f2_xyz, normW, normF2, idxq, x);
      unsigned int* d32 = (unsigned int*)(X1 + (size_t)row*96);
      union { unsigned int u; _Float16 h[2]; } pk;
      #pragma unroll
      for (int c=0;c<35;c++){
        pk.h[0] = (_Float16)x[2*c]; pk.h[1] = (_Float16)x[2*c+1];
        d32[c] = pk.u;
      }
      #pragma unroll
      for (int c=35;c<48;c++) d32[c] = 0u;
    }
    if (tid < 128){ ssum[tid]=0.f; sssq[tid]=0.f; }
    __syncthreads();
    int wave = tid >> 6;
    int quad = lane >> 4, n16 = lane & 15;
    float r1[8], r2[8];
    #pragma unroll
    for (int i=0;i<8;i++){ r1[i]=0.f; r2[i]=0.f; }
    for (int t=0;t<4;t++){
      int m0 = blk*256 + t*64 + wave*16;
      const _Float16* xr = X1 + (size_t)(m0 + n16)*96 + quad*8;
      f16x8 a0 = *(const f16x8*)(xr);
      f16x8 a1 = *(const f16x8*)(xr + 32);
      f16x8 a2 = *(const f16x8*)(xr + 64);
      #pragma unroll
      for (int nt = 0; nt < 8; nt++){
        const _Float16* wr = w1h + (size_t)(nt*16 + n16)*96 + quad*8;
        f16x8 b0 = *(const f16x8*)(wr);
        f16x8 b1 = *(const f16x8*)(wr + 32);
        f16x8 b2 = *(const f16x8*)(wr + 64);
        f32x4 acc = {0.f,0.f,0.f,0.f};
        acc = __builtin_amdgcn_mfma_f32_16x16x32_f16(a0, b0, acc, 0,0,0);
        acc = __builtin_amdgcn_mfma_f32_16x16x32_f16(a1, b1, acc, 0,0,0);
        acc = __builtin_amdgcn_mfma_f32_16x16x32_f16(a2, b2, acc, 0,0,0);
        float s1 = acc[0]+acc[1]+acc[2]+acc[3];
        float s2 = acc[0]*acc[0]+acc[1]*acc[1]+acc[2]*acc[2]+acc[3]*acc[3];
        s1 += __shfl_xor(s1, 16, 64); s1 += __shfl_xor(s1, 32, 64);
        s2 += __shfl_xor(s2, 16, 64); s2 += __shfl_xor(s2, 32, 64);
        r1[nt] += s1; r2[nt] += s2;
      }
    }
    if (quad == 0){
      #pragma unroll
      for (int nt=0;nt<8;nt++){
        atomicAdd(&ssum[nt*16+n16], r1[nt]); atomicAdd(&sssq[nt*16+n16], r2[nt]);
      }
    }
    __syncthreads();
    if (tid < 128){ atomicAdd(&stats[tid], ssum[tid]); atomicAdd(&stats[128+tid], sssq[tid]); }
  } else if (blk < 1088){
    float a[28];
    #pragma unroll
    for (int q=0;q<28;q++) a[q]=0.f;
    int g = (blk-1024)*256 + tid;
    for (int s=0;s<16;s++){
      int row = g + s*16384;
      int p = row >> 5, b = p >> 12;
      int idx = idxq[row];
      const float* wx = wxyz + (size_t)p*3;
      const float* fx = f2_xyz + ((size_t)b*Nn + idx)*3;
      float xt[7] = {wx[0],wx[1],wx[2],fx[0],fx[1],fx[2],1.f};
      int q=0;
      #pragma unroll
      for (int i=0;i<7;i++)
        #pragma unroll
        for (int j=i;j<7;j++) a[q++] += xt[i]*xt[j];
    }
    if (tid < 28) sacc[tid]=0.f;
    __syncthreads();
    #pragma unroll
    for (int q=0;q<28;q++){
      float v = wred64(a[q]);
      if (lane==0) atomicAdd(&sacc[q], v);
    }
    __syncthreads();
    if (tid < 28) atomicAdd(&gram[tid], sacc[tid]);
  } else {
    float a[66];
    #pragma unroll
    for (int q=0;q<66;q++) a[q]=0.f;
    int g = (blk-1088)*256 + tid;
    for (int s=0;s<16;s++){
      int row = g + s*8192;
      float x[10];
      build_x10(row, wxyz, idx2, x);
      float xt[11] = {x[0],x[1],x[2],x[3],x[4],x[5],x[6],x[7],x[8],x[9],1.f};
      int q=0;
      #pragma unroll
      for (int i=0;i<11;i++)
        #pragma unroll
        for (int j=i;j<11;j++) a[q++] += xt[i]*xt[j];
    }
    if (tid < 66) sacc[tid]=0.f;
    __syncthreads();
    #pragma unroll
    for (int q=0;q<66;q++){
      float v = wred64(a[q]);
      if (lane==0) atomicAdd(&sacc[q], v);
    }
    __syncthreads();
    if (tid < 66) atomicAdd(&gram[32+tid], sacc[tid]);
  }
}

__global__ __launch_bounds__(128) void k_gram_fin(
    const float* __restrict__ gram,
    const float* __restrict__ piw, const float* __restrict__ pib,
    const float* __restrict__ pcw, const float* __restrict__ pcb,
    float* stats)
{
  int tid = threadIdx.x;
  if (tid < 64){
    int c = tid;
    float wt[7];
    #pragma unroll
    for (int i=0;i<6;i++) wt[i] = piw[i*64+c];
    wt[6] = pib[c];
    const float* G = gram;
    float sum=0.f, ssq=0.f;
    #pragma unroll
    for (int i=0;i<7;i++){
      int offi = i*7 - (i*(i-1))/2;
      sum += wt[i]*G[offi + (6-i)];
      #pragma unroll
      for (int j=0;j<7;j++){
        int ii = i<j? i : j, jj = i<j? j : i;
        int o = ii*7 - (ii*(ii-1))/2 + (jj-ii);
        ssq += wt[i]*wt[j]*G[o];
      }
    }
    stats[2*256+c] = sum; stats[2*256+128+c] = ssq;
  } else {
    int c = tid-64;
    float wt[11];
    #pragma unroll
    for (int i=0;i<10;i++) wt[i] = pcw[i*64+c];
    wt[10] = pcb[c];
    const float* G = gram + 32;
    float sum=0.f, ssq=0.f;
    #pragma unroll
    for (int i=0;i<11;i++){
      int offi = i*11 - (i*(i-1))/2;
      sum += wt[i]*G[offi + (10-i)];
      #pragma unroll
      for (int j=0;j<11;j++){
        int ii = i<j? i : j, jj = i<j? j : i;
        int o = ii*11 - (ii*(ii-1))/2 + (jj-ii);
        ssq += wt[i]*wt[j]*G[o];
      }
    }
    stats[5*256+c] = sum; stats[5*256+128+c] = ssq;
  }
}

// ---------------- MFMA m1: 4 tiles/block; y1 -> BN/leaky -> t (LDS) -> x W2 -> y2 ----------------
__global__ __launch_bounds__(256) void k_mfma_m1(
    const _Float16* __restrict__ X1, const _Float16* __restrict__ w1h,
    const _Float16* __restrict__ w2h,
    const float* __restrict__ m1g0, const float* __restrict__ m1e0,
    float* stats, _Float16* __restrict__ y2h)
{
  __shared__ _Float16 st[64*136];
  __shared__ float sc1[128], sh1[128], ssum[64], sssq[64];
  int tid = threadIdx.x;
  if (tid < 128){
    float s,h; bn_param(stats, tid, INV_R1, m1g0, m1e0, s, h);
    sc1[tid]=s; sh1[tid]=h;
  }
  if (tid < 64){ ssum[tid]=0.f; sssq[tid]=0.f; }
  __syncthreads();
  int wave = tid >> 6, lane = tid & 63;
  int quad = lane >> 4, n16 = lane & 15;
  float r1[4], r2[4];
  #pragma unroll
  for (int i=0;i<4;i++){ r1[i]=0.f; r2[i]=0.f; }
  for (int t=0;t<4;t++){
    int m0 = blockIdx.x*256 + t*64 + wave*16;
    const _Float16* xr = X1 + (size_t)(m0 + n16)*96 + quad*8;
    f16x8 a0 = *(const f16x8*)(xr);
    f16x8 a1 = *(const f16x8*)(xr + 32);
    f16x8 a2 = *(const f16x8*)(xr + 64);
    #pragma unroll
    for (int nt = 0; nt < 8; nt++){
      const _Float16* wr = w1h + (size_t)(nt*16 + n16)*96 + quad*8;
      f16x8 b0 = *(const f16x8*)(wr);
      f16x8 b1 = *(const f16x8*)(wr + 32);
      f16x8 b2 = *(const f16x8*)(wr + 64);
      f32x4 acc = {0.f,0.f,0.f,0.f};
      acc = __builtin_amdgcn_mfma_f32_16x16x32_f16(a0, b0, acc, 0,0,0);
      acc = __builtin_amdgcn_mfma_f32_16x16x32_f16(a1, b1, acc, 0,0,0);
      acc = __builtin_amdgcn_mfma_f32_16x16x32_f16(a2, b2, acc, 0,0,0);
      int ch = nt*16 + n16;
      float sc = sc1[ch], sh = sh1[ch];
      #pragma unroll
      for (int r=0;r<4;r++){
        float v = leakyf(acc[r]*sc + sh);
        st[(size_t)(wave*16 + quad*4 + r)*136 + ch] = (_Float16)v;
      }
    }
    __syncthreads();
    const _Float16* tr = st + (size_t)(wave*16 + n16)*136 + quad*8;
    f16x8 t0 = *(const f16x8*)(tr);
    f16x8 t1 = *(const f16x8*)(tr + 32);
    f16x8 t2 = *(const f16x8*)(tr + 64);
    f16x8 t3 = *(const f16x8*)(tr + 96);
    #pragma unroll
    for (int nt = 0; nt < 4; nt++){
      const _Float16* wr = w2h + (size_t)(nt*16 + n16)*128 + quad*8;
      f16x8 b0 = *(const f16x8*)(wr);
      f16x8 b1 = *(const f16x8*)(wr + 32);
      f16x8 b2 = *(const f16x8*)(wr + 64);
      f16x8 b3 = *(const f16x8*)(wr + 96);
      f32x4 acc = {0.f,0.f,0.f,0.f};
      acc = __builtin_amdgcn_mfma_f32_16x16x32_f16(t0, b0, acc, 0,0,0);
      acc = __builtin_amdgcn_mfma_f32_16x16x32_f16(t1, b1, acc, 0,0,0);
      acc = __builtin_amdgcn_mfma_f32_16x16x32_f16(t2, b2, acc, 0,0,0);
      acc = __builtin_amdgcn_mfma_f32_16x16x32_f16(t3, b3, acc, 0,0,0);
      int ch = nt*16 + n16;
      #pragma unroll
      for (int r=0;r<4;r++){
        int rowg = blockIdx.x*256 + t*64 + wave*16 + quad*4 + r;
        y2h[(size_t)rowg*64 + ch] = (_Float16)acc[r];
      }
      float s1 = acc[0]+acc[1]+acc[2]+acc[3];
      float s2 = acc[0]*acc[0]+acc[1]*acc[1]+acc[2]*acc[2]+acc[3]*acc[3];
      s1 += __shfl_xor(s1, 16, 64); s1 += __shfl_xor(s1, 32, 64);
      s2 += __shfl_xor(s2, 16, 64); s2 += __shfl_xor(s2, 32, 64);
      r1[nt] += s1; r2[nt] += s2;
    }
    __syncthreads();
  }
  if (quad == 0){
    #pragma unroll
    for (int nt=0;nt<4;nt++){
      atomicAdd(&ssum[nt*16+n16], r1[nt]); atomicAdd(&sssq[nt*16+n16], r2[nt]);
    }
  }
  __syncthreads();
  if (tid < 64){ atomicAdd(&stats[1*256+tid], ssum[tid]); atomicAdd(&stats[1*256+128+tid], sssq[tid]); }
}

// ---------------- MFMA m2a: 4 tiles/block; u=[pi_enc|feat] in LDS, y3 = u x W3 ----------------
__global__ __launch_bounds__(256) void k_mfma_m2a(
    const float* __restrict__ wxyz, const float* __restrict__ f2_xyz,
    const int* __restrict__ idxq,
    const float* __restrict__ piwT, const float* __restrict__ pib,
    const float* __restrict__ pig, const float* __restrict__ pie,
    const float* __restrict__ m1g1, const float* __restrict__ m1e1,
    const _Float16* __restrict__ y2h, const _Float16* __restrict__ w3h,
    float* stats, _Float16* __restrict__ y3h)
{
  __shared__ _Float16 su[64*136];
  __shared__ float spw[384];
  __shared__ float scp[64], shp[64], sc2[64], sh2[64], ssum[64], sssq[64];
  int tid = threadIdx.x;
  for (int d = tid; d < 384; d += 256) spw[d] = piwT[d];
  if (tid < 64){
    float s,h;
    bn_param(stats+2*256, tid, INV_R1, pig,  pie,  s, h); scp[tid]=s; shp[tid]=h;
    bn_param(stats+1*256, tid, INV_R1, m1g1, m1e1, s, h); sc2[tid]=s; sh2[tid]=h;
    ssum[tid]=0.f; sssq[tid]=0.f;
  }
  __syncthreads();
  int r = tid & 63, cg = tid >> 6;
  int wave = tid >> 6, lane = tid & 63, quad = lane >> 4, n16 = lane & 15;
  float r1[4], r2[4];
  #pragma unroll
  for (int i=0;i<4;i++){ r1[i]=0.f; r2[i]=0.f; }
  for (int t=0;t<4;t++){
    int rowg = blockIdx.x*256 + t*64 + r;
    {
      int p = rowg >> 5, b = p >> 12;
      int idx = idxq[rowg];
      const float* wx = wxyz + (size_t)p*3;
      const float* fx = f2_xyz + ((size_t)b*Nn + idx)*3;
      float x0=wx[0],x1=wx[1],x2=wx[2],x3=fx[0],x4=fx[1],x5=fx[2];
      #pragma unroll
      for (int jj=0;jj<16;jj++){
        int j = cg*16 + jj;
        const float* pw = spw + j*6;
        float e = pib[j] + x0*pw[0]+x1*pw[1]+x2*pw[2]+x3*pw[3]+x4*pw[4]+x5*pw[5];
        su[r*136 + j] = (_Float16)leakyf(e*scp[j] + shp[j]);
      }
      const f16x8* yr = (const f16x8*)(y2h + (size_t)rowg*64 + cg*16);
      f16x8 q0 = yr[0], q1 = yr[1];
      #pragma unroll
      for (int jj=0;jj<8;jj++){
        int c = cg*16 + jj;
        su[r*136 + 64 + c] = (_Float16)leakyf((float)q0[jj]*sc2[c] + sh2[c]);
      }
      #pragma unroll
      for (int jj=0;jj<8;jj++){
        int c = cg*16 + 8 + jj;
        su[r*136 + 64 + c] = (_Float16)leakyf((float)q1[jj]*sc2[c] + sh2[c]);
      }
    }
    __syncthreads();
    const _Float16* ur = su + (size_t)(wave*16 + n16)*136 + quad*8;
    f16x8 a0 = *(const f16x8*)(ur);
    f16x8 a1 = *(const f16x8*)(ur + 32);
    f16x8 a2 = *(const f16x8*)(ur + 64);
    f16x8 a3 = *(const f16x8*)(ur + 96);
    #pragma unroll
    for (int nt = 0; nt < 4; nt++){
      const _Float16* wr = w3h + (size_t)(nt*16 + n16)*128 + quad*8;
      f16x8 b0 = *(const f16x8*)(wr);
      f16x8 b1 = *(const f16x8*)(wr + 32);
      f16x8 b2 = *(const f16x8*)(wr + 64);
      f16x8 b3 = *(const f16x8*)(wr + 96);
      f32x4 acc = {0.f,0.f,0.f,0.f};
      acc = __builtin_amdgcn_mfma_f32_16x16x32_f16(a0, b0, acc, 0,0,0);
      acc = __builtin_amdgcn_mfma_f32_16x16x32_f16(a1, b1, acc, 0,0,0);
      acc = __builtin_amdgcn_mfma_f32_16x16x32_f16(a2, b2, acc, 0,0,0);
      acc = __builtin_amdgcn_mfma_f32_16x16x32_f16(a3, b3, acc, 0,0,0);
      int ch = nt*16 + n16;
      #pragma unroll
      for (int rr=0;rr<4;rr++){
        int rg = blockIdx.x*256 + t*64 + wave*16 + quad*4 + rr;
        y3h[(size_t)rg*64 + ch] = (_Float16)acc[rr];
      }
      float s1 = acc[0]+acc[1]+acc[2]+acc[3];
      float s2 = acc[0]*acc[0]+acc[1]*acc[1]+acc[2]*acc[2]+acc[3]*acc[3];
      s1 += __shfl_xor(s1, 16, 64); s1 += __shfl_xor(s1, 32, 64);
      s2 += __shfl_xor(s2, 16, 64); s2 += __shfl_xor(s2, 32, 64);
      r1[nt] += s1; r2[nt] += s2;
    }
    __syncthreads();
  }
  if (quad == 0){
    #pragma unroll
    for (int nt=0;nt<4;nt++){
      atomicAdd(&ssum[nt*16+n16], r1[nt]); atomicAdd(&sssq[nt*16+n16], r2[nt]);
    }
  }
  __syncthreads();
  if (tid < 64){ atomicAdd(&stats[3*256+tid], ssum[tid]); atomicAdd(&stats[3*256+128+tid], sssq[tid]); }
}

// ---------------- generic MFMA pointwise 64->64, 4 tiles/block ----------------
__global__ __launch_bounds__(256) void k_mfma_pw64(
    const _Float16* __restrict__ yin, const _Float16* __restrict__ wh,
    const float* __restrict__ g, const float* __restrict__ e,
    const float* statsIn, float* statsOut, float inv_n,
    _Float16* __restrict__ yout)
{
  __shared__ _Float16 stt[64*72];
  __shared__ float sc[64], sh[64], ssum[64], sssq[64];
  int tid = threadIdx.x;
  if (tid < 64){
    float s,h; bn_param(statsIn, tid, inv_n, g, e, s, h);
    sc[tid]=s; sh[tid]=h; ssum[tid]=0.f; sssq[tid]=0.f;
  }
  __syncthreads();
  int r = tid & 63, cg = tid >> 6;
  int wave = tid >> 6, lane = tid & 63, quad = lane >> 4, n16 = lane & 15;
  float r1[4], r2[4];
  #pragma unroll
  for (int i=0;i<4;i++){ r1[i]=0.f; r2[i]=0.f; }
  for (int t=0;t<4;t++){
    int rowg = blockIdx.x*256 + t*64 + r;
    const f16x8* yr = (const f16x8*)(yin + (size_t)rowg*64 + cg*16);
    f16x8 q0 = yr[0], q1 = yr[1];
    #pragma unroll
    for (int jj=0;jj<8;jj++){
      int c = cg*16 + jj;
      stt[r*72 + c] = (_Float16)leakyf((float)q0[jj]*sc[c] + sh[c]);
    }
    #pragma unroll
    for (int jj=0;jj<8;jj++){
      int c = cg*16 + 8 + jj;
      stt[r*72 + c] = (_Float16)leakyf((float)q1[jj]*sc[c] + sh[c]);
    }
    __syncthreads();
    const _Float16* tr = stt + (size_t)(wave*16 + n16)*72 + quad*8;
    f16x8 a0 = *(const f16x8*)(tr);
    f16x8 a1 = *(const f16x8*)(tr + 32);
    #pragma unroll
    for (int nt = 0; nt < 4; nt++){
      const _Float16* wr = wh + (size_t)(nt*16 + n16)*64 + quad*8;
      f16x8 b0 = *(const f16x8*)(wr);
      f16x8 b1 = *(const f16x8*)(wr + 32);
      f32x4 acc = {0.f,0.f,0.f,0.f};
      acc = __builtin_amdgcn_mfma_f32_16x16x32_f16(a0, b0, acc, 0,0,0);
      acc = __builtin_amdgcn_mfma_f32_16x16x32_f16(a1, b1, acc, 0,0,0);
      int ch = nt*16 + n16;
      #pragma unroll
      for (int rr=0;rr<4;rr++){
        int rg = blockIdx.x*256 + t*64 + wave*16 + quad*4 + rr;
        yout[(size_t)rg*64 + ch] = (_Float16)acc[rr];
      }
      float s1 = acc[0]+acc[1]+acc[2]+acc[3];
      float s2 = acc[0]*acc[0]+acc[1]*acc[1]+acc[2]*acc[2]+acc[3]*acc[3];
      s1 += __shfl_xor(s1, 16, 64); s1 += __shfl_xor(s1, 32, 64);
      s2 += __shfl_xor(s2, 16, 64); s2 += __shfl_xor(s2, 32, 64);
      r1[nt] += s1; r2[nt] += s2;
    }
    __syncthreads();
  }
  if (quad == 0){
    #pragma unroll
    for (int nt=0;nt<4;nt++){
      atomicAdd(&ssum[nt*16+n16], r1[nt]); atomicAdd(&sssq[nt*16+n16], r2[nt]);
    }
  }
  __syncthreads();
  if (tid < 64){ atomicAdd(&statsOut[tid], ssum[tid]); atomicAdd(&statsOut[128+tid], sssq[tid]); }
}

// ---------------- MFMA m3a: 4 tiles/block; v=[pc_enc|wp|pif1_g] (192ch), y5 = v x W5 ----------------
__global__ __launch_bounds__(256) void k_mfma_m3a(
    const float* __restrict__ wxyz, const float* __restrict__ warped_points,
    const _Float16* __restrict__ pif1h, const int* __restrict__ idx2,
    const float* __restrict__ pcwT, const float* __restrict__ pcb,
    const float* __restrict__ pcg, const float* __restrict__ pce,
    const _Float16* __restrict__ w5h,
    float* stats, _Float16* __restrict__ y5h)
{
  __shared__ _Float16 sv[64*200];
  __shared__ float spw[640];
  __shared__ float scp[64], shp[64], ssum[64], sssq[64];
  int tid = threadIdx.x;
  for (int d = tid; d < 640; d += 256) spw[d] = pcwT[d];
  if (tid < 64){
    float s,h; bn_param(stats+5*256, tid, INV_R2, pcg, pce, s, h);
    scp[tid]=s; shp[tid]=h; ssum[tid]=0.f; sssq[tid]=0.f;
  }
  __syncthreads();
  int r = tid & 63, cg = tid >> 6;
  int wave = tid >> 6, lane = tid & 63, quad = lane >> 4, n16 = lane & 15;
  float r1[4], r2[4];
  #pragma unroll
  for (int i=0;i<4;i++){ r1[i]=0.f; r2[i]=0.f; }
  for (int t=0;t<4;t++){
    int rowg = blockIdx.x*256 + t*64 + r;
    {
      int p = rowg >> 4, b = p >> 12;
      int idx = idx2[rowg];
      float x[10];
      build_x10(rowg, wxyz, idx2, x);
      #pragma unroll
      for (int jj=0;jj<16;jj++){
        int j = cg*16 + jj;
        const float* pw = spw + j*10;
        float e = pcb[j];
        #pragma unroll
        for (int i=0;i<10;i++) e += x[i]*pw[i];
        sv[r*200 + j] = (_Float16)leakyf(e*scp[j] + shp[j]);
      }
      const float4* wp = (const float4*)(warped_points + (size_t)p*64 + cg*16);
      #pragma unroll
      for (int v4=0; v4<4; v4++){
        float4 q = wp[v4];
        int c = 64 + cg*16 + v4*4;
        sv[r*200 + c + 0] = (_Float16)q.x;
        sv[r*200 + c + 1] = (_Float16)q.y;
        sv[r*200 + c + 2] = (_Float16)q.z;
        sv[r*200 + c + 3] = (_Float16)q.w;
      }
      const f16x8* pg = (const f16x8*)(pif1h + ((size_t)(b*HWn) + idx)*64 + cg*16);
      f16x8 g0 = pg[0], g1 = pg[1];
      #pragma unroll
      for (int jj=0;jj<8;jj++) sv[r*200 + 128 + cg*16 + jj] = g0[jj];
      #pragma unroll
      for (int jj=0;jj<8;jj++) sv[r*200 + 136 + cg*16 + jj] = g1[jj];
    }
    __syncthreads();
    const _Float16* vr = sv + (size_t)(wave*16 + n16)*200 + quad*8;
    f16x8 a0 = *(const f16x8*)(vr);
    f16x8 a1 = *(const f16x8*)(vr + 32);
    f16x8 a2 = *(const f16x8*)(vr + 64);
    f16x8 a3 = *(const f16x8*)(vr + 96);
    f16x8 a4 = *(const f16x8*)(vr + 128);
    f16x8 a5 = *(const f16x8*)(vr + 160);
    #pragma unroll
    for (int nt = 0; nt < 4; nt++){
      const _Float16* wr = w5h + (size_t)(nt*16 + n16)*192 + quad*8;
      f32x4 acc = {0.f,0.f,0.f,0.f};
      acc = __builtin_amdgcn_mfma_f32_16x16x32_f16(a0, *(const f16x8*)(wr),       acc, 0,0,0);
      acc = __builtin_amdgcn_mfma_f32_16x16x32_f16(a1, *(const f16x8*)(wr + 32),  acc, 0,0,0);
      acc = __builtin_amdgcn_mfma_f32_16x16x32_f16(a2, *(const f16x8*)(wr + 64),  acc, 0,0,0);
      acc = __builtin_amdgcn_mfma_f32_16x16x32_f16(a3, *(const f16x8*)(wr + 96),  acc, 0,0,0);
      acc = __builtin_amdgcn_mfma_f32_16x16x32_f16(a4, *(const f16x8*)(wr + 128), acc, 0,0,0);
      acc = __builtin_amdgcn_mfma_f32_16x16x32_f16(a5, *(const f16x8*)(wr + 160), acc, 0,0,0);
      int ch = nt*16 + n16;
      #pragma unroll
      for (int rr=0;rr<4;rr++){
        int rg = blockIdx.x*256 + t*64 + wave*16 + quad*4 + rr;
        y5h[(size_t)rg*64 + ch] = (_Float16)acc[rr];
      }
      float s1 = acc[0]+acc[1]+acc[2]+acc[3];
      float s2 = acc[0]*acc[0]+acc[1]*acc[1]+acc[2]*acc[2]+acc[3]*acc[3];
      s1 += __shfl_xor(s1, 16, 64); s1 += __shfl_xor(s1, 32, 64);
      s2 += __shfl_xor(s2, 16, 64); s2 += __shfl_xor(s2, 32, 64);
      r1[nt] += s1; r2[nt] += s2;
    }
    __syncthreads();
  }
  if (quad == 0){
    #pragma unroll
    for (int nt=0;nt<4;nt++){
      atomicAdd(&ssum[nt*16+n16], r1[nt]); atomicAdd(&sssq[nt*16+n16], r2[nt]);
    }
  }
  __syncthreads();
  if (tid < 64){ atomicAdd(&stats[6*256+tid], ssum[tid]); atomicAdd(&stats[6*256+128+tid], sssq[tid]); }
}

// ---------------- stage-1 softmax over KQ, weighted sum of feat -> pif1 (f16) ----------------
__global__ __launch_bounds__(256) void k_softmax1(
    const _Float16* __restrict__ y2h, const _Float16* __restrict__ y4h,
    const float* stats,
    const float* __restrict__ m1g1, const float* __restrict__ m1e1,
    const float* __restrict__ m2g1, const float* __restrict__ m2e1,
    _Float16* __restrict__ pif1h)
{
  int tid = threadIdx.x, lane = tid & 63;
  int p = blockIdx.x*4 + (tid >> 6);
  int d = lane;
  float sc2,sh2,sc4,sh4;
  bn_param(stats+1*256, d, INV_R1, m1g1, m1e1, sc2, sh2);
  bn_param(stats+4*256, d, INV_R1, m2g1, m2e1, sc4, sh4);
  size_t rb = (size_t)p*KQn;
  float v[32]; float mx = -1e30f;
  #pragma unroll
  for (int k=0;k<32;k++){
    float t = leakyf((float)y4h[(rb+k)*64 + d]*sc4 + sh4);
    v[k] = t; mx = fmaxf(mx, t);
  }
  float se = 0.f;
  #pragma unroll
  for (int k=0;k<32;k++){ float ev = __expf(v[k]-mx); v[k]=ev; se += ev; }
  float inv = 1.f/se, acc = 0.f;
  #pragma unroll
  for (int k=0;k<32;k++){
    float f = leakyf((float)y2h[(rb+k)*64 + d]*sc2 + sh2);
    acc += v[k]*f;
  }
  pif1h[(size_t)p*64 + d] = (_Float16)(acc*inv);
}

// ---------------- stage-2 masked softmax over KN, weighted sum of gathered pif1 ----------------
__global__ __launch_bounds__(256) void k_softmax2(
    const _Float16* __restrict__ y6h, const _Float16* __restrict__ pif1h,
    const int* __restrict__ idx2, const float* __restrict__ validf,
    const float* stats,
    const float* __restrict__ m3g1, const float* __restrict__ m3e1,
    float* __restrict__ out)
{
  int tid = threadIdx.x, lane = tid & 63;
  int p = blockIdx.x*4 + (tid >> 6);
  int b = p >> 12;
  int d = lane;
  float sc,sh; bn_param(stats+7*256, d, INV_R2, m3g1, m3e1, sc, sh);
  size_t rb = (size_t)p*KNn;
  float v[16]; float mx = -1e30f;
  #pragma unroll
  for (int k=0;k<16;k++){
    float t = leakyf((float)y6h[(rb+k)*64 + d]*sc + sh);
    t = (validf[rb+k] > 0.5f) ? t : -1e10f;
    v[k] = t; mx = fmaxf(mx, t);
  }
  float se = 0.f;
  #pragma unroll
  for (int k=0;k<16;k++){ float ev = __expf(v[k]-mx); v[k]=ev; se += ev; }
  float inv = 1.f/se, acc = 0.f;
  #pragma unroll
  for (int k=0;k<16;k++){
    int idx = idx2[rb+k];
    acc += v[k]*(float)pif1h[((size_t)(b*HWn) + idx)*64 + d];
  }
  out[(size_t)p*64 + d] = acc*inv;
}

// ---------------- launcher ----------------
extern "C" void kernel_launch(void* const* d_in, const int* in_sizes, int n_in,
                              void* d_out, int out_size, void* d_ws, size_t ws_size,
                              hipStream_t stream)
{
  (void)in_sizes; (void)n_in; (void)out_size; (void)ws_size;
  const float* xyz_proj      = (const float*)d_in[0];
  const float* warped_xyz    = (const float*)d_in[1];
  const float* warped_points = (const float*)d_in[2];
  const float* f2_xyz        = (const float*)d_in[4];
  const float* f2_points     = (const float*)d_in[5];
  const float* lidar_z       = (const float*)d_in[6];
  const float* m1w0=(const float*)d_in[7],  *m1g0=(const float*)d_in[9],  *m1e0=(const float*)d_in[10];
  const float* m1w1=(const float*)d_in[11], *m1g1=(const float*)d_in[13], *m1e1=(const float*)d_in[14];
  const float* piw =(const float*)d_in[15], *pib =(const float*)d_in[16], *pig =(const float*)d_in[17], *pie =(const float*)d_in[18];
  const float* m2w0=(const float*)d_in[19], *m2g0=(const float*)d_in[21], *m2e0=(const float*)d_in[22];
  const float* m2w1=(const float*)d_in[23], *m2g1=(const float*)d_in[25], *m2e1=(const float*)d_in[26];
  const float* pcw =(const float*)d_in[27], *pcb =(const float*)d_in[28], *pcg =(const float*)d_in[29], *pce =(const float*)d_in[30];
  const float* m3w0=(const float*)d_in[31], *m3g0=(const float*)d_in[33], *m3e0=(const float*)d_in[34];
  const float* m3w1=(const float*)d_in[35], *m3g1=(const float*)d_in[37], *m3e1=(const float*)d_in[38];
  float* out = (float*)d_out;

  float* ws     = (float*)d_ws;
  float* wxyz   = ws;                        // 24576
  float* normW  = wxyz   + 24576;            // 524288
  float* normF2 = normW  + 524288;           // 524288
  float* piwT   = normF2 + 524288;           // 384
  float* pcwT   = piwT   + 384;              // 640
  float* stats  = pcwT   + 640;              // 2048
  float* gram   = stats  + 2048;             // 128
  int*   idxq   = (int*)(gram + 128);        // 262144
  int*   idx2   = idxq   + 262144;           // 131072
  float* validf = (float*)(idx2 + 131072);   // 131072
  _Float16* pif1h = (_Float16*)(validf + 131072);   // 1048576 f16 = 524288 floats
  float* X1f    = validf + 131072 + 524288;
  _Float16* X1  = (_Float16*)X1f;            // 25165824 f16 = 12582912 floats
  float* y2f    = X1f + 12582912;
  _Float16* y2h = (_Float16*)y2f;            // 16777216 f16 = 8388608 floats
  float* y3f    = y2f + 8388608;
  _Float16* y3h = (_Float16*)y3f;            // 8388608 floats
  float* whb    = y3f + 8388608;             // f16 weights: 49152 f16 = 24576 floats
  _Float16* w1h = (_Float16*)whb;            // 12288
  _Float16* w2h = w1h + 12288;               // 8192
  _Float16* w3h = w2h + 8192;                // 8192
  _Float16* w4h = w3h + 8192;                // 4096
  _Float16* w5h = w4h + 4096;                // 12288
  _Float16* w6h = w5h + 12288;               // 4096
  // aliases (regions dead by the time they're overwritten):
  _Float16* y4h = (_Float16*)X1f;            // X1 dead after k_mfma_m1
  _Float16* y5h = (_Float16*)(X1f + 8388608);
  _Float16* y6h = y3h;                       // y3 dead after first k_mfma_pw64

  hipMemsetAsync(stats, 0, (2048+128)*sizeof(float), stream);
  k_prep<<<4388,256,0,stream>>>(warped_xyz, lidar_z, warped_points, f2_points,
                                m1w0, m1w1, piw, pcw, m2w0, m2w1, m3w0, m3w1,
                                wxyz, normW, normF2, piwT, pcwT,
                                w1h, w2h, w3h, w4h, w5h, w6h);
  k_knn_all<<<16384,256,0,stream>>>(warped_xyz, f2_xyz, idxq,
                                    xyz_proj, xyz_proj, idx2, validf);
  k_build_stats<<<1120,256,0,stream>>>(wxyz, f2_xyz, normW, normF2, idxq, idx2,
                                       w1h, X1, stats, gram);
  k_gram_fin<<<1,128,0,stream>>>(gram, piw, pib, pcw, pcb, stats);
  k_mfma_m1<<<1024,256,0,stream>>>(X1, w1h, w2h, m1g0, m1e0, stats, y2h);
  k_mfma_m2a<<<1024,256,0,stream>>>(wxyz, f2_xyz, idxq, piwT, pib, pig, pie,
                                    m1g1, m1e1, y2h, w3h, stats, y3h);
  k_mfma_pw64<<<1024,256,0,stream>>>(y3h, w4h, m2g0, m2e0,
                                     stats+3*256, stats+4*256, INV_R1, y4h);
  k_softmax1<<<2048,256,0,stream>>>(y2h, y4h, stats, m1g1, m1e1, m2g1, m2e1, pif1h);
  k_mfma_m3a<<<512,256,0,stream>>>(wxyz, warped_points, pif1h, idx2,
                                   pcwT, pcb, pcg, pce, w5h, stats, y5h);
  k_mfma_pw64<<<512,256,0,stream>>>(y5h, w6h, m3g0, m3e0,
                                    stats+6*256, stats+7*256, INV_R2, y6h);
  k_softmax2<<<2048,256,0,stream>>>(y6h, pif1h, idx2, validf, stats, m3g1, m3e1, out);
}

// Round 12
// 514.883 us; speedup vs baseline: 1.0706x; 1.0706x over previous
//
#include <hip/hip_runtime.h>
#include <math.h>

// ---------------- problem constants ----------------
constexpr int Bn  = 2;
constexpr int HWn = 4096;     // H*W
constexpr int Nn  = 4096;
constexpr int KQn = 32;
constexpr int KNn = 16;
constexpr float INV_R1 = 1.0f/262144.0f;   // exact pow2
constexpr float INV_R2 = 1.0f/131072.0f;   // exact pow2

typedef _Float16 f16x8 __attribute__((ext_vector_type(8)));
typedef float    f32x4 __attribute__((ext_vector_type(4)));

__device__ __forceinline__ float wred64(float v){
  #pragma unroll
  for (int m = 32; m > 0; m >>= 1) v += __shfl_xor(v, m, 64);
  return v;
}
__device__ __forceinline__ float leakyf(float v){ return v > 0.f ? v : 0.1f*v; }

__device__ __forceinline__ void bn_param(const float* st, int c, float inv_n,
                                         const float* g, const float* e,
                                         float& sc, float& sh){
  float mu  = st[c]*inv_n;
  float var = st[128+c]*inv_n - mu*mu;
  float s   = g[c]*rsqrtf(var + 1e-5f);
  sc = s; sh = e[c] - mu*s;
}

// Build the 70-channel stage-1 input row: [wxyz(3), f2_xyz[idx](3), normW*normF2(64)]
__device__ __forceinline__ void build_x70(int row,
    const float* __restrict__ wxyz, const float* __restrict__ f2_xyz,
    const float* __restrict__ normW, const float* __restrict__ normF2,
    const int* __restrict__ idxq, float* x){
  int p = row >> 5;
  int b = p >> 12;
  int idx = idxq[row];
  const float* wx = wxyz + (size_t)p*3;
  const float* fx = f2_xyz + ((size_t)b*Nn + idx)*3;
  x[0]=wx[0]; x[1]=wx[1]; x[2]=wx[2];
  x[3]=fx[0]; x[4]=fx[1]; x[5]=fx[2];
  const float4* nw = (const float4*)(normW  + (size_t)p*64);
  const float4* nf = (const float4*)(normF2 + ((size_t)b*Nn + idx)*64);
  #pragma unroll
  for (int c=0;c<16;c++){
    float4 a = nw[c], q = nf[c];
    x[6+4*c+0]=a.x*q.x; x[6+4*c+1]=a.y*q.y; x[6+4*c+2]=a.z*q.z; x[6+4*c+3]=a.w*q.w;
  }
}

// Build the 10-channel stage-2 geometry row
__device__ __forceinline__ void build_x10(int row,
    const float* __restrict__ wxyz, const int* __restrict__ idx2, float* x){
  int p = row >> 4, b = p >> 12;
  int idx = idx2[row];
  const float* nw = wxyz + (size_t)p*3;
  const float* gw = wxyz + ((size_t)b*HWn + idx)*3;
  float n0=nw[0],n1=nw[1],n2=nw[2];
  float g0=gw[0],g1=gw[1],g2=gw[2];
  float d0=g0-n0, d1=g1-n1, d2=g2-n2;
  x[0]=n0;x[1]=n1;x[2]=n2; x[3]=g0;x[4]=g1;x[5]=g2;
  x[6]=d0;x[7]=d1;x[8]=d2; x[9]=sqrtf(d0*d0+d1*d1+d2*d2+1e-20f);
}

// ---------------- prep: norms, wxyz, weight transposes + f16 weights ----------------
__global__ __launch_bounds__(256) void k_prep(
    const float* __restrict__ warped_xyz, const float* __restrict__ lidar_z,
    const float* __restrict__ warped_points, const float* __restrict__ f2_points,
    const float* __restrict__ m1w0, const float* __restrict__ m1w1,
    const float* __restrict__ piw, const float* __restrict__ pcw,
    const float* __restrict__ m2w0, const float* __restrict__ m2w1,
    const float* __restrict__ m3w0, const float* __restrict__ m3w1,
    float* __restrict__ wxyz, float* __restrict__ normW, float* __restrict__ normF2,
    float* __restrict__ piwT, float* __restrict__ pcwT,
    _Float16* __restrict__ w1h, _Float16* __restrict__ w2h,
    _Float16* __restrict__ w3h, _Float16* __restrict__ w4h,
    _Float16* __restrict__ w5h, _Float16* __restrict__ w6h)
{
  int blk = blockIdx.x, tid = threadIdx.x;
  if (blk < 4096){
    int lane = tid & 63;
    int p = blk*4 + (tid >> 6);            // 0..16383
    const float* src; float* dst;
    if (p < Bn*HWn){ src = warped_points + (size_t)p*64; dst = normW + (size_t)p*64; }
    else { int q = p - Bn*HWn; src = f2_points + (size_t)q*64; dst = normF2 + (size_t)q*64; }
    float x = src[lane];
    float m = wred64(x) * (1.f/64.f);
    float d = x - m;
    float ss = wred64(d*d);
    float s = fmaxf(sqrtf(ss*(1.f/63.f)), 1e-12f);
    dst[lane] = d / s;
  } else if (blk < 4192){
    int e = (blk-4096)*256 + tid;          // < 24576
    wxyz[e] = warped_xyz[e] * lidar_z[e/3];
  } else if (blk < 4196){
    int e = (blk-4192)*256 + tid;          // < 1024
    if (e < 384){ piwT[(e & 63)*6  + (e >> 6)] = piw[e]; }
    else if (e < 1024){ int f = e-384; pcwT[(f & 63)*10 + (f >> 6)] = pcw[f]; }
  } else {
    int e = (blk-4196)*256 + tid;          // < 49152
    if (e < 12288){                        // w1h[j][k] : [128 out][96 in-pad]
      int j = e/96, k = e - j*96;
      w1h[e] = (k < 70) ? (_Float16)m1w0[k*128 + j] : (_Float16)0.f;
    } else if (e < 20480){                 // w2h[d][c] : [64][128]
      int f = e - 12288; int d = f >> 7, c = f & 127;
      w2h[f] = (_Float16)m1w1[c*64 + d];
    } else if (e < 28672){                 // w3h[d][c] : [64][128]
      int f = e - 20480; int d = f >> 7, c = f & 127;
      w3h[f] = (_Float16)m2w0[c*64 + d];
    } else if (e < 32768){                 // w4h[d][c] : [64][64]
      int f = e - 28672; int d = f >> 6, c = f & 63;
      w4h[f] = (_Float16)m2w1[c*64 + d];
    } else if (e < 45056){                 // w5h[d][c] : [64][192]
      int f = e - 32768; int d = f/192, c = f - 192*d;
      w5h[f] = (_Float16)m3w0[c*64 + d];
    } else {                               // w6h[d][c] : [64][64]
      int f = e - 45056; int d = f >> 6, c = f & 63;
      w6h[f] = (_Float16)m3w1[c*64 + d];
    }
  }
}

// ---------------- exact k-smallest: 12-bit first-digit radix select ----------------
// Pass 1 uses 4096 bins over the informative bits [L-11, L] of (key - blockmin):
// expected bucket size ~1 => atomics spread (no serialization), class==rem => exit
// after one pass. Fallback 8-bit passes for residual ties. Both kNN problems in
// one launch: blocks 0..8191 = KQ(32), 8192..16383 = KN(16)+valid.
__global__ __launch_bounds__(256) void k_knn_all(
    const float* __restrict__ qA, const float* __restrict__ pA, int* __restrict__ oA,
    const float* __restrict__ qB, const float* __restrict__ pB, int* __restrict__ oB,
    float* __restrict__ ovalid)
{
  __shared__ int hist[4096];
  __shared__ int wsum[4];
  __shared__ unsigned int redm[4], redM[4];
  __shared__ int sh_sel, sh_rem, sh_cls, cnt_lt, cnt_eq;
  bool second = blockIdx.x >= 8192;
  int blk = second ? (blockIdx.x - 8192) : blockIdx.x;
  int K = second ? KNn : KQn;
  const float* qpts = second ? qB : qA;
  const float* pts  = second ? pB : pA;
  int* oidx = second ? oB : oA;
  int b = blk >> 12;
  int qi = blk & 4095;
  int tid = threadIdx.x;
  int lane = tid & 63, wv = tid >> 6;
  const float* qp = qpts + ((size_t)(b*HWn+qi))*3;
  float qx=qp[0], qy=qp[1], qz=qp[2];
  const float* pb = pts + (size_t)b*Nn*3;
  unsigned int key[16];
  {
    const float4* pb4 = (const float4*)(pb + (size_t)tid*48);  // 16 pts = 48 floats
    float4 v[12];
    #pragma unroll
    for (int i=0;i<12;i++) v[i] = pb4[i];
    const float* f = (const float*)v;
    #pragma unroll
    for (int i=0;i<16;i++){
      float dx = __fsub_rn(qx, f[i*3+0]);
      float dy = __fsub_rn(qy, f[i*3+1]);
      float dz = __fsub_rn(qz, f[i*3+2]);
      float d2 = __fadd_rn(__fadd_rn(__fmul_rn(dx,dx), __fmul_rn(dy,dy)), __fmul_rn(dz,dz));
      key[i] = __float_as_uint(d2);        // nonneg floats: uint order == float order
    }
  }
  // block min/max of keys
  unsigned int mn = key[0], mx = key[0];
  #pragma unroll
  for (int i=1;i<16;i++){ mn = min(mn, key[i]); mx = max(mx, key[i]); }
  #pragma unroll
  for (int m=32;m>0;m>>=1){
    mn = min(mn, (unsigned int)__shfl_xor((int)mn, m, 64));
    mx = max(mx, (unsigned int)__shfl_xor((int)mx, m, 64));
  }
  if (lane == 0){ redm[wv] = mn; redM[wv] = mx; }
  if (tid == 0){ cnt_lt = 0; cnt_eq = 0; }
  __syncthreads();
  mn = min(min(redm[0],redm[1]), min(redm[2],redm[3]));
  mx = max(max(redM[0],redM[1]), max(redM[2],redM[3]));
  unsigned int R = mx - mn;
  int L = (R == 0u) ? 0 : (31 - __clz(R));
  int shift = (L > 11) ? (L - 11) : 0;
  unsigned int dmask = 4095u;

  unsigned int active = 0xFFFFu, below = 0u;
  int rem = K;
  bool first = true;
  for (;;){
    __syncthreads();                       // guard hist reuse
    if (first){
      int4 z = {0,0,0,0};
      #pragma unroll
      for (int j=0;j<4;j++) ((int4*)hist)[tid + j*256] = z;
    } else {
      hist[tid] = 0;
    }
    __syncthreads();
    #pragma unroll
    for (int i=0;i<16;i++){
      if (active & (1u<<i))
        atomicAdd(&hist[(int)(((key[i]-mn) >> shift) & dmask)], 1);
    }
    __syncthreads();
    if (first){
      // hierarchical scan over 4096 bins: 16/thread
      int base = tid*16;
      int hv[16]; int tot = 0;
      #pragma unroll
      for (int i=0;i<16;i++){ hv[i] = hist[base+i]; tot += hv[i]; }
      int pref = tot;
      #pragma unroll
      for (int m=1;m<64;m<<=1){ int t = __shfl_up(pref, m, 64); if (lane >= m) pref += t; }
      if (lane == 63) wsum[wv] = pref;
      __syncthreads();
      int off = 0;
      #pragma unroll
      for (int i=0;i<3;i++) if (i < wv) off += wsum[i];
      pref += off;                         // inclusive prefix of thread totals
      if (pref >= rem && (pref - tot) < rem){
        int running = pref - tot;
        bool done = false;
        #pragma unroll
        for (int i=0;i<16;i++){
          if (!done && running + hv[i] >= rem){
            sh_sel = base + i;
            sh_rem = rem - running;
            sh_cls = hv[i];
            done = true;
          }
          if (!done) running += hv[i];
        }
      }
    } else {
      int h = hist[tid];
      int pref = h;
      #pragma unroll
      for (int m=1;m<64;m<<=1){ int t = __shfl_up(pref, m, 64); if (lane >= m) pref += t; }
      if (lane == 63) wsum[wv] = pref;
      __syncthreads();
      int off = 0;
      #pragma unroll
      for (int i=0;i<3;i++) if (i < wv) off += wsum[i];
      pref += off;
      if (pref >= rem && (pref - h) < rem){
        sh_sel = tid;
        sh_rem = rem - (pref - h);
        sh_cls = h;
      }
    }
    __syncthreads();
    unsigned int sel = (unsigned int)sh_sel; rem = sh_rem; int cls = sh_cls;
    #pragma unroll
    for (int i=0;i<16;i++){
      if (active & (1u<<i)){
        unsigned int d = ((key[i]-mn) >> shift) & dmask;
        if (d < sel) below |= (1u<<i);
        if (d != sel) active &= ~(1u<<i);
      }
    }
    if (cls == rem || shift == 0) break;
    int w = (shift < 8) ? shift : 8;
    shift -= w;
    dmask = (w == 8) ? 255u : ((1u<<w) - 1u);
    first = false;
  }
  // output: all 'below' + rem of the final equal-class
  size_t obase = ((size_t)(b*HWn+qi))*K;
  int nless = K - rem;
  const unsigned int U100 = __float_as_uint(100.0f);  // DIST*DIST
  #pragma unroll
  for (int i=0;i<16;i++){
    if (below & (1u<<i)){
      int s = atomicAdd(&cnt_lt, 1);
      oidx[obase+s] = tid*16 + i;
      if (second) ovalid[obase+s] = (key[i] < U100) ? 1.f : 0.f;
    } else if (active & (1u<<i)){
      int s = atomicAdd(&cnt_eq, 1);
      if (s < rem){
        oidx[obase+nless+s] = tid*16 + i;
        if (second) ovalid[obase+nless+s] = (key[i] < U100) ? 1.f : 0.f;
      }
    }
  }
}

// ---------------- fused: build X1 rows + y1 stats MFMA + Gram matrices ----------------
__global__ __launch_bounds__(256) void k_build_stats(
    const float* __restrict__ wxyz, const float* __restrict__ f2_xyz,
    const float* __restrict__ normW, const float* __restrict__ normF2,
    const int* __restrict__ idxq, const int* __restrict__ idx2,
    const _Float16* __restrict__ w1h,
    _Float16* __restrict__ X1, float* stats, float* __restrict__ gram)
{
  __shared__ float ssum[128], sssq[128];
  __shared__ float sacc[66];
  int blk = blockIdx.x, tid = threadIdx.x, lane = tid & 63;
  if (blk < 1024){
    int row = blk*256 + tid;
    {
      float x[70];
      build_x70(row, wxyz, f2_xyz, normW, normF2, idxq, x);
      unsigned int* d32 = (unsigned int*)(X1 + (size_t)row*96);
      union { unsigned int u; _Float16 h[2]; } pk;
      #pragma unroll
      for (int c=0;c<35;c++){
        pk.h[0] = (_Float16)x[2*c]; pk.h[1] = (_Float16)x[2*c+1];
        d32[c] = pk.u;
      }
      #pragma unroll
      for (int c=35;c<48;c++) d32[c] = 0u;
    }
    if (tid < 128){ ssum[tid]=0.f; sssq[tid]=0.f; }
    __syncthreads();
    int wave = tid >> 6;
    int quad = lane >> 4, n16 = lane & 15;
    float r1[8], r2[8];
    #pragma unroll
    for (int i=0;i<8;i++){ r1[i]=0.f; r2[i]=0.f; }
    for (int t=0;t<4;t++){
      int m0 = blk*256 + t*64 + wave*16;
      const _Float16* xr = X1 + (size_t)(m0 + n16)*96 + quad*8;
      f16x8 a0 = *(const f16x8*)(xr);
      f16x8 a1 = *(const f16x8*)(xr + 32);
      f16x8 a2 = *(const f16x8*)(xr + 64);
      #pragma unroll
      for (int nt = 0; nt < 8; nt++){
        const _Float16* wr = w1h + (size_t)(nt*16 + n16)*96 + quad*8;
        f16x8 b0 = *(const f16x8*)(wr);
        f16x8 b1 = *(const f16x8*)(wr + 32);
        f16x8 b2 = *(const f16x8*)(wr + 64);
        f32x4 acc = {0.f,0.f,0.f,0.f};
        acc = __builtin_amdgcn_mfma_f32_16x16x32_f16(a0, b0, acc, 0,0,0);
        acc = __builtin_amdgcn_mfma_f32_16x16x32_f16(a1, b1, acc, 0,0,0);
        acc = __builtin_amdgcn_mfma_f32_16x16x32_f16(a2, b2, acc, 0,0,0);
        float s1 = acc[0]+acc[1]+acc[2]+acc[3];
        float s2 = acc[0]*acc[0]+acc[1]*acc[1]+acc[2]*acc[2]+acc[3]*acc[3];
        s1 += __shfl_xor(s1, 16, 64); s1 += __shfl_xor(s1, 32, 64);
        s2 += __shfl_xor(s2, 16, 64); s2 += __shfl_xor(s2, 32, 64);
        r1[nt] += s1; r2[nt] += s2;
      }
    }
    if (quad == 0){
      #pragma unroll
      for (int nt=0;nt<8;nt++){
        atomicAdd(&ssum[nt*16+n16], r1[nt]); atomicAdd(&sssq[nt*16+n16], r2[nt]);
      }
    }
    __syncthreads();
    if (tid < 128){ atomicAdd(&stats[tid], ssum[tid]); atomicAdd(&stats[128+tid], sssq[tid]); }
  } else if (blk < 1088){
    float a[28];
    #pragma unroll
    for (int q=0;q<28;q++) a[q]=0.f;
    int g = (blk-1024)*256 + tid;
    for (int s=0;s<16;s++){
      int row = g + s*16384;
      int p = row >> 5, b = p >> 12;
      int idx = idxq[row];
      const float* wx = wxyz + (size_t)p*3;
      const float* fx = f2_xyz + ((size_t)b*Nn + idx)*3;
      float xt[7] = {wx[0],wx[1],wx[2],fx[0],fx[1],fx[2],1.f};
      int q=0;
      #pragma unroll
      for (int i=0;i<7;i++)
        #pragma unroll
        for (int j=i;j<7;j++) a[q++] += xt[i]*xt[j];
    }
    if (tid < 28) sacc[tid]=0.f;
    __syncthreads();
    #pragma unroll
    for (int q=0;q<28;q++){
      float v = wred64(a[q]);
      if (lane==0) atomicAdd(&sacc[q], v);
    }
    __syncthreads();
    if (tid < 28) atomicAdd(&gram[tid], sacc[tid]);
  } else {
    float a[66];
    #pragma unroll
    for (int q=0;q<66;q++) a[q]=0.f;
    int g = (blk-1088)*256 + tid;
    for (int s=0;s<16;s++){
      int row = g + s*8192;
      float x[10];
      build_x10(row, wxyz, idx2, x);
      float xt[11] = {x[0],x[1],x[2],x[3],x[4],x[5],x[6],x[7],x[8],x[9],1.f};
      int q=0;
      #pragma unroll
      for (int i=0;i<11;i++)
        #pragma unroll
        for (int j=i;j<11;j++) a[q++] += xt[i]*xt[j];
    }
    if (tid < 66) sacc[tid]=0.f;
    __syncthreads();
    #pragma unroll
    for (int q=0;q<66;q++){
      float v = wred64(a[q]);
      if (lane==0) atomicAdd(&sacc[q], v);
    }
    __syncthreads();
    if (tid < 66) atomicAdd(&gram[32+tid], sacc[tid]);
  }
}

__global__ __launch_bounds__(128) void k_gram_fin(
    const float* __restrict__ gram,
    const float* __restrict__ piw, const float* __restrict__ pib,
    const float* __restrict__ pcw, const float* __restrict__ pcb,
    float* stats)
{
  int tid = threadIdx.x;
  if (tid < 64){
    int c = tid;
    float wt[7];
    #pragma unroll
    for (int i=0;i<6;i++) wt[i] = piw[i*64+c];
    wt[6] = pib[c];
    const float* G = gram;
    float sum=0.f, ssq=0.f;
    #pragma unroll
    for (int i=0;i<7;i++){
      int offi = i*7 - (i*(i-1))/2;
      sum += wt[i]*G[offi + (6-i)];
      #pragma unroll
      for (int j=0;j<7;j++){
        int ii = i<j? i : j, jj = i<j? j : i;
        int o = ii*7 - (ii*(ii-1))/2 + (jj-ii);
        ssq += wt[i]*wt[j]*G[o];
      }
    }
    stats[2*256+c] = sum; stats[2*256+128+c] = ssq;
  } else {
    int c = tid-64;
    float wt[11];
    #pragma unroll
    for (int i=0;i<10;i++) wt[i] = pcw[i*64+c];
    wt[10] = pcb[c];
    const float* G = gram + 32;
    float sum=0.f, ssq=0.f;
    #pragma unroll
    for (int i=0;i<11;i++){
      int offi = i*11 - (i*(i-1))/2;
      sum += wt[i]*G[offi + (10-i)];
      #pragma unroll
      for (int j=0;j<11;j++){
        int ii = i<j? i : j, jj = i<j? j : i;
        int o = ii*11 - (ii*(ii-1))/2 + (jj-ii);
        ssq += wt[i]*wt[j]*G[o];
      }
    }
    stats[5*256+c] = sum; stats[5*256+128+c] = ssq;
  }
}

// ---------------- MFMA m1: 4 tiles/block; y1 -> BN/leaky -> t (LDS) -> x W2 -> y2 ----------------
__global__ __launch_bounds__(256) void k_mfma_m1(
    const _Float16* __restrict__ X1, const _Float16* __restrict__ w1h,
    const _Float16* __restrict__ w2h,
    const float* __restrict__ m1g0, const float* __restrict__ m1e0,
    float* stats, _Float16* __restrict__ y2h)
{
  __shared__ _Float16 st[64*136];
  __shared__ float sc1[128], sh1[128], ssum[64], sssq[64];
  int tid = threadIdx.x;
  if (tid < 128){
    float s,h; bn_param(stats, tid, INV_R1, m1g0, m1e0, s, h);
    sc1[tid]=s; sh1[tid]=h;
  }
  if (tid < 64){ ssum[tid]=0.f; sssq[tid]=0.f; }
  __syncthreads();
  int wave = tid >> 6, lane = tid & 63;
  int quad = lane >> 4, n16 = lane & 15;
  float r1[4], r2[4];
  #pragma unroll
  for (int i=0;i<4;i++){ r1[i]=0.f; r2[i]=0.f; }
  for (int t=0;t<4;t++){
    int m0 = blockIdx.x*256 + t*64 + wave*16;
    const _Float16* xr = X1 + (size_t)(m0 + n16)*96 + quad*8;
    f16x8 a0 = *(const f16x8*)(xr);
    f16x8 a1 = *(const f16x8*)(xr + 32);
    f16x8 a2 = *(const f16x8*)(xr + 64);
    #pragma unroll
    for (int nt = 0; nt < 8; nt++){
      const _Float16* wr = w1h + (size_t)(nt*16 + n16)*96 + quad*8;
      f16x8 b0 = *(const f16x8*)(wr);
      f16x8 b1 = *(const f16x8*)(wr + 32);
      f16x8 b2 = *(const f16x8*)(wr + 64);
      f32x4 acc = {0.f,0.f,0.f,0.f};
      acc = __builtin_amdgcn_mfma_f32_16x16x32_f16(a0, b0, acc, 0,0,0);
      acc = __builtin_amdgcn_mfma_f32_16x16x32_f16(a1, b1, acc, 0,0,0);
      acc = __builtin_amdgcn_mfma_f32_16x16x32_f16(a2, b2, acc, 0,0,0);
      int ch = nt*16 + n16;
      float sc = sc1[ch], sh = sh1[ch];
      #pragma unroll
      for (int r=0;r<4;r++){
        float v = leakyf(acc[r]*sc + sh);
        st[(size_t)(wave*16 + quad*4 + r)*136 + ch] = (_Float16)v;
      }
    }
    __syncthreads();
    const _Float16* tr = st + (size_t)(wave*16 + n16)*136 + quad*8;
    f16x8 t0 = *(const f16x8*)(tr);
    f16x8 t1 = *(const f16x8*)(tr + 32);
    f16x8 t2 = *(const f16x8*)(tr + 64);
    f16x8 t3 = *(const f16x8*)(tr + 96);
    #pragma unroll
    for (int nt = 0; nt < 4; nt++){
      const _Float16* wr = w2h + (size_t)(nt*16 + n16)*128 + quad*8;
      f16x8 b0 = *(const f16x8*)(wr);
      f16x8 b1 = *(const f16x8*)(wr + 32);
      f16x8 b2 = *(const f16x8*)(wr + 64);
      f16x8 b3 = *(const f16x8*)(wr + 96);
      f32x4 acc = {0.f,0.f,0.f,0.f};
      acc = __builtin_amdgcn_mfma_f32_16x16x32_f16(t0, b0, acc, 0,0,0);
      acc = __builtin_amdgcn_mfma_f32_16x16x32_f16(t1, b1, acc, 0,0,0);
      acc = __builtin_amdgcn_mfma_f32_16x16x32_f16(t2, b2, acc, 0,0,0);
      acc = __builtin_amdgcn_mfma_f32_16x16x32_f16(t3, b3, acc, 0,0,0);
      int ch = nt*16 + n16;
      #pragma unroll
      for (int r=0;r<4;r++){
        int rowg = blockIdx.x*256 + t*64 + wave*16 + quad*4 + r;
        y2h[(size_t)rowg*64 + ch] = (_Float16)acc[r];
      }
      float s1 = acc[0]+acc[1]+acc[2]+acc[3];
      float s2 = acc[0]*acc[0]+acc[1]*acc[1]+acc[2]*acc[2]+acc[3]*acc[3];
      s1 += __shfl_xor(s1, 16, 64); s1 += __shfl_xor(s1, 32, 64);
      s2 += __shfl_xor(s2, 16, 64); s2 += __shfl_xor(s2, 32, 64);
      r1[nt] += s1; r2[nt] += s2;
    }
    __syncthreads();
  }
  if (quad == 0){
    #pragma unroll
    for (int nt=0;nt<4;nt++){
      atomicAdd(&ssum[nt*16+n16], r1[nt]); atomicAdd(&sssq[nt*16+n16], r2[nt]);
    }
  }
  __syncthreads();
  if (tid < 64){ atomicAdd(&stats[1*256+tid], ssum[tid]); atomicAdd(&stats[1*256+128+tid], sssq[tid]); }
}

// ---------------- MFMA m2a: 4 tiles/block; u=[pi_enc|feat] in LDS, y3 = u x W3 ----------------
__global__ __launch_bounds__(256) void k_mfma_m2a(
    const float* __restrict__ wxyz, const float* __restrict__ f2_xyz,
    const int* __restrict__ idxq,
    const float* __restrict__ piwT, const float* __restrict__ pib,
    const float* __restrict__ pig, const float* __restrict__ pie,
    const float* __restrict__ m1g1, const float* __restrict__ m1e1,
    const _Float16* __restrict__ y2h, const _Float16* __restrict__ w3h,
    float* stats, _Float16* __restrict__ y3h)
{
  __shared__ _Float16 su[64*136];
  __shared__ float spw[384];
  __shared__ float scp[64], shp[64], sc2[64], sh2[64], ssum[64], sssq[64];
  int tid = threadIdx.x;
  for (int d = tid; d < 384; d += 256) spw[d] = piwT[d];
  if (tid < 64){
    float s,h;
    bn_param(stats+2*256, tid, INV_R1, pig,  pie,  s, h); scp[tid]=s; shp[tid]=h;
    bn_param(stats+1*256, tid, INV_R1, m1g1, m1e1, s, h); sc2[tid]=s; sh2[tid]=h;
    ssum[tid]=0.f; sssq[tid]=0.f;
  }
  __syncthreads();
  int r = tid & 63, cg = tid >> 6;
  int wave = tid >> 6, lane = tid & 63, quad = lane >> 4, n16 = lane & 15;
  float r1[4], r2[4];
  #pragma unroll
  for (int i=0;i<4;i++){ r1[i]=0.f; r2[i]=0.f; }
  for (int t=0;t<4;t++){
    int rowg = blockIdx.x*256 + t*64 + r;
    {
      int p = rowg >> 5, b = p >> 12;
      int idx = idxq[rowg];
      const float* wx = wxyz + (size_t)p*3;
      const float* fx = f2_xyz + ((size_t)b*Nn + idx)*3;
      float x0=wx[0],x1=wx[1],x2=wx[2],x3=fx[0],x4=fx[1],x5=fx[2];
      #pragma unroll
      for (int jj=0;jj<16;jj++){
        int j = cg*16 + jj;
        const float* pw = spw + j*6;
        float e = pib[j] + x0*pw[0]+x1*pw[1]+x2*pw[2]+x3*pw[3]+x4*pw[4]+x5*pw[5];
        su[r*136 + j] = (_Float16)leakyf(e*scp[j] + shp[j]);
      }
      const f16x8* yr = (const f16x8*)(y2h + (size_t)rowg*64 + cg*16);
      f16x8 q0 = yr[0], q1 = yr[1];
      #pragma unroll
      for (int jj=0;jj<8;jj++){
        int c = cg*16 + jj;
        su[r*136 + 64 + c] = (_Float16)leakyf((float)q0[jj]*sc2[c] + sh2[c]);
      }
      #pragma unroll
      for (int jj=0;jj<8;jj++){
        int c = cg*16 + 8 + jj;
        su[r*136 + 64 + c] = (_Float16)leakyf((float)q1[jj]*sc2[c] + sh2[c]);
      }
    }
    __syncthreads();
    const _Float16* ur = su + (size_t)(wave*16 + n16)*136 + quad*8;
    f16x8 a0 = *(const f16x8*)(ur);
    f16x8 a1 = *(const f16x8*)(ur + 32);
    f16x8 a2 = *(const f16x8*)(ur + 64);
    f16x8 a3 = *(const f16x8*)(ur + 96);
    #pragma unroll
    for (int nt = 0; nt < 4; nt++){
      const _Float16* wr = w3h + (size_t)(nt*16 + n16)*128 + quad*8;
      f16x8 b0 = *(const f16x8*)(wr);
      f16x8 b1 = *(const f16x8*)(wr + 32);
      f16x8 b2 = *(const f16x8*)(wr + 64);
      f16x8 b3 = *(const f16x8*)(wr + 96);
      f32x4 acc = {0.f,0.f,0.f,0.f};
      acc = __builtin_amdgcn_mfma_f32_16x16x32_f16(a0, b0, acc, 0,0,0);
      acc = __builtin_amdgcn_mfma_f32_16x16x32_f16(a1, b1, acc, 0,0,0);
      acc = __builtin_amdgcn_mfma_f32_16x16x32_f16(a2, b2, acc, 0,0,0);
      acc = __builtin_amdgcn_mfma_f32_16x16x32_f16(a3, b3, acc, 0,0,0);
      int ch = nt*16 + n16;
      #pragma unroll
      for (int rr=0;rr<4;rr++){
        int rg = blockIdx.x*256 + t*64 + wave*16 + quad*4 + rr;
        y3h[(size_t)rg*64 + ch] = (_Float16)acc[rr];
      }
      float s1 = acc[0]+acc[1]+acc[2]+acc[3];
      float s2 = acc[0]*acc[0]+acc[1]*acc[1]+acc[2]*acc[2]+acc[3]*acc[3];
      s1 += __shfl_xor(s1, 16, 64); s1 += __shfl_xor(s1, 32, 64);
      s2 += __shfl_xor(s2, 16, 64); s2 += __shfl_xor(s2, 32, 64);
      r1[nt] += s1; r2[nt] += s2;
    }
    __syncthreads();
  }
  if (quad == 0){
    #pragma unroll
    for (int nt=0;nt<4;nt++){
      atomicAdd(&ssum[nt*16+n16], r1[nt]); atomicAdd(&sssq[nt*16+n16], r2[nt]);
    }
  }
  __syncthreads();
  if (tid < 64){ atomicAdd(&stats[3*256+tid], ssum[tid]); atomicAdd(&stats[3*256+128+tid], sssq[tid]); }
}

// ---------------- generic MFMA pointwise 64->64, 4 tiles/block ----------------
__global__ __launch_bounds__(256) void k_mfma_pw64(
    const _Float16* __restrict__ yin, const _Float16* __restrict__ wh,
    const float* __restrict__ g, const float* __restrict__ e,
    const float* statsIn, float* statsOut, float inv_n,
    _Float16* __restrict__ yout)
{
  __shared__ _Float16 stt[64*72];
  __shared__ float sc[64], sh[64], ssum[64], sssq[64];
  int tid = threadIdx.x;
  if (tid < 64){
    float s,h; bn_param(statsIn, tid, inv_n, g, e, s, h);
    sc[tid]=s; sh[tid]=h; ssum[tid]=0.f; sssq[tid]=0.f;
  }
  __syncthreads();
  int r = tid & 63, cg = tid >> 6;
  int wave = tid >> 6, lane = tid & 63, quad = lane >> 4, n16 = lane & 15;
  float r1[4], r2[4];
  #pragma unroll
  for (int i=0;i<4;i++){ r1[i]=0.f; r2[i]=0.f; }
  for (int t=0;t<4;t++){
    int rowg = blockIdx.x*256 + t*64 + r;
    const f16x8* yr = (const f16x8*)(yin + (size_t)rowg*64 + cg*16);
    f16x8 q0 = yr[0], q1 = yr[1];
    #pragma unroll
    for (int jj=0;jj<8;jj++){
      int c = cg*16 + jj;
      stt[r*72 + c] = (_Float16)leakyf((float)q0[jj]*sc[c] + sh[c]);
    }
    #pragma unroll
    for (int jj=0;jj<8;jj++){
      int c = cg*16 + 8 + jj;
      stt[r*72 + c] = (_Float16)leakyf((float)q1[jj]*sc[c] + sh[c]);
    }
    __syncthreads();
    const _Float16* tr = stt + (size_t)(wave*16 + n16)*72 + quad*8;
    f16x8 a0 = *(const f16x8*)(tr);
    f16x8 a1 = *(const f16x8*)(tr + 32);
    #pragma unroll
    for (int nt = 0; nt < 4; nt++){
      const _Float16* wr = wh + (size_t)(nt*16 + n16)*64 + quad*8;
      f16x8 b0 = *(const f16x8*)(wr);
      f16x8 b1 = *(const f16x8*)(wr + 32);
      f32x4 acc = {0.f,0.f,0.f,0.f};
      acc = __builtin_amdgcn_mfma_f32_16x16x32_f16(a0, b0, acc, 0,0,0);
      acc = __builtin_amdgcn_mfma_f32_16x16x32_f16(a1, b1, acc, 0,0,0);
      int ch = nt*16 + n16;
      #pragma unroll
      for (int rr=0;rr<4;rr++){
        int rg = blockIdx.x*256 + t*64 + wave*16 + quad*4 + rr;
        yout[(size_t)rg*64 + ch] = (_Float16)acc[rr];
      }
      float s1 = acc[0]+acc[1]+acc[2]+acc[3];
      float s2 = acc[0]*acc[0]+acc[1]*acc[1]+acc[2]*acc[2]+acc[3]*acc[3];
      s1 += __shfl_xor(s1, 16, 64); s1 += __shfl_xor(s1, 32, 64);
      s2 += __shfl_xor(s2, 16, 64); s2 += __shfl_xor(s2, 32, 64);
      r1[nt] += s1; r2[nt] += s2;
    }
    __syncthreads();
  }
  if (quad == 0){
    #pragma unroll
    for (int nt=0;nt<4;nt++){
      atomicAdd(&ssum[nt*16+n16], r1[nt]); atomicAdd(&sssq[nt*16+n16], r2[nt]);
    }
  }
  __syncthreads();
  if (tid < 64){ atomicAdd(&statsOut[tid], ssum[tid]); atomicAdd(&statsOut[128+tid], sssq[tid]); }
}

// ---------------- MFMA m3a: 4 tiles/block; v=[pc_enc|wp|pif1_g] (192ch), y5 = v x W5 ----------------
__global__ __launch_bounds__(256) void k_mfma_m3a(
    const float* __restrict__ wxyz, const float* __restrict__ warped_points,
    const _Float16* __restrict__ pif1h, const int* __restrict__ idx2,
    const float* __restrict__ pcwT, const float* __restrict__ pcb,
    const float* __restrict__ pcg, const float* __restrict__ pce,
    const _Float16* __restrict__ w5h,
    float* stats, _Float16* __restrict__ y5h)
{
  __shared__ _Float16 sv[64*200];
  __shared__ float spw[640];
  __shared__ float scp[64], shp[64], ssum[64], sssq[64];
  int tid = threadIdx.x;
  for (int d = tid; d < 640; d += 256) spw[d] = pcwT[d];
  if (tid < 64){
    float s,h; bn_param(stats+5*256, tid, INV_R2, pcg, pce, s, h);
    scp[tid]=s; shp[tid]=h; ssum[tid]=0.f; sssq[tid]=0.f;
  }
  __syncthreads();
  int r = tid & 63, cg = tid >> 6;
  int wave = tid >> 6, lane = tid & 63, quad = lane >> 4, n16 = lane & 15;
  float r1[4], r2[4];
  #pragma unroll
  for (int i=0;i<4;i++){ r1[i]=0.f; r2[i]=0.f; }
  for (int t=0;t<4;t++){
    int rowg = blockIdx.x*256 + t*64 + r;
    {
      int p = rowg >> 4, b = p >> 12;
      int idx = idx2[rowg];
      float x[10];
      build_x10(rowg, wxyz, idx2, x);
      #pragma unroll
      for (int jj=0;jj<16;jj++){
        int j = cg*16 + jj;
        const float* pw = spw + j*10;
        float e = pcb[j];
        #pragma unroll
        for (int i=0;i<10;i++) e += x[i]*pw[i];
        sv[r*200 + j] = (_Float16)leakyf(e*scp[j] + shp[j]);
      }
      const float4* wp = (const float4*)(warped_points + (size_t)p*64 + cg*16);
      #pragma unroll
      for (int v4=0; v4<4; v4++){
        float4 q = wp[v4];
        int c = 64 + cg*16 + v4*4;
        sv[r*200 + c + 0] = (_Float16)q.x;
        sv[r*200 + c + 1] = (_Float16)q.y;
        sv[r*200 + c + 2] = (_Float16)q.z;
        sv[r*200 + c + 3] = (_Float16)q.w;
      }
      const f16x8* pg = (const f16x8*)(pif1h + ((size_t)(b*HWn) + idx)*64 + cg*16);
      f16x8 g0 = pg[0], g1 = pg[1];
      #pragma unroll
      for (int jj=0;jj<8;jj++) sv[r*200 + 128 + cg*16 + jj] = g0[jj];
      #pragma unroll
      for (int jj=0;jj<8;jj++) sv[r*200 + 136 + cg*16 + jj] = g1[jj];
    }
    __syncthreads();
    const _Float16* vr = sv + (size_t)(wave*16 + n16)*200 + quad*8;
    f16x8 a0 = *(const f16x8*)(vr);
    f16x8 a1 = *(const f16x8*)(vr + 32);
    f16x8 a2 = *(const f16x8*)(vr + 64);
    f16x8 a3 = *(const f16x8*)(vr + 96);
    f16x8 a4 = *(const f16x8*)(vr + 128);
    f16x8 a5 = *(const f16x8*)(vr + 160);
    #pragma unroll
    for (int nt = 0; nt < 4; nt++){
      const _Float16* wr = w5h + (size_t)(nt*16 + n16)*192 + quad*8;
      f32x4 acc = {0.f,0.f,0.f,0.f};
      acc = __builtin_amdgcn_mfma_f32_16x16x32_f16(a0, *(const f16x8*)(wr),       acc, 0,0,0);
      acc = __builtin_amdgcn_mfma_f32_16x16x32_f16(a1, *(const f16x8*)(wr + 32),  acc, 0,0,0);
      acc = __builtin_amdgcn_mfma_f32_16x16x32_f16(a2, *(const f16x8*)(wr + 64),  acc, 0,0,0);
      acc = __builtin_amdgcn_mfma_f32_16x16x32_f16(a3, *(const f16x8*)(wr + 96),  acc, 0,0,0);
      acc = __builtin_amdgcn_mfma_f32_16x16x32_f16(a4, *(const f16x8*)(wr + 128), acc, 0,0,0);
      acc = __builtin_amdgcn_mfma_f32_16x16x32_f16(a5, *(const f16x8*)(wr + 160), acc, 0,0,0);
      int ch = nt*16 + n16;
      #pragma unroll
      for (int rr=0;rr<4;rr++){
        int rg = blockIdx.x*256 + t*64 + wave*16 + quad*4 + rr;
        y5h[(size_t)rg*64 + ch] = (_Float16)acc[rr];
      }
      float s1 = acc[0]+acc[1]+acc[2]+acc[3];
      float s2 = acc[0]*acc[0]+acc[1]*acc[1]+acc[2]*acc[2]+acc[3]*acc[3];
      s1 += __shfl_xor(s1, 16, 64); s1 += __shfl_xor(s1, 32, 64);
      s2 += __shfl_xor(s2, 16, 64); s2 += __shfl_xor(s2, 32, 64);
      r1[nt] += s1; r2[nt] += s2;
    }
    __syncthreads();
  }
  if (quad == 0){
    #pragma unroll
    for (int nt=0;nt<4;nt++){
      atomicAdd(&ssum[nt*16+n16], r1[nt]); atomicAdd(&sssq[nt*16+n16], r2[nt]);
    }
  }
  __syncthreads();
  if (tid < 64){ atomicAdd(&stats[6*256+tid], ssum[tid]); atomicAdd(&stats[6*256+128+tid], sssq[tid]); }
}

// ---------------- stage-1 softmax over KQ, weighted sum of feat -> pif1 (f16) ----------------
__global__ __launch_bounds__(256) void k_softmax1(
    const _Float16* __restrict__ y2h, const _Float16* __restrict__ y4h,
    const float* stats,
    const float* __restrict__ m1g1, const float* __restrict__ m1e1,
    const float* __restrict__ m2g1, const float* __restrict__ m2e1,
    _Float16* __restrict__ pif1h)
{
  int tid = threadIdx.x, lane = tid & 63;
  int p = blockIdx.x*4 + (tid >> 6);
  int d = lane;
  float sc2,sh2,sc4,sh4;
  bn_param(stats+1*256, d, INV_R1, m1g1, m1e1, sc2, sh2);
  bn_param(stats+4*256, d, INV_R1, m2g1, m2e1, sc4, sh4);
  size_t rb = (size_t)p*KQn;
  float v[32]; float mx = -1e30f;
  #pragma unroll
  for (int k=0;k<32;k++){
    float t = leakyf((float)y4h[(rb+k)*64 + d]*sc4 + sh4);
    v[k] = t; mx = fmaxf(mx, t);
  }
  float se = 0.f;
  #pragma unroll
  for (int k=0;k<32;k++){ float ev = __expf(v[k]-mx); v[k]=ev; se += ev; }
  float inv = 1.f/se, acc = 0.f;
  #pragma unroll
  for (int k=0;k<32;k++){
    float f = leakyf((float)y2h[(rb+k)*64 + d]*sc2 + sh2);
    acc += v[k]*f;
  }
  pif1h[(size_t)p*64 + d] = (_Float16)(acc*inv);
}

// ---------------- stage-2 masked softmax over KN, weighted sum of gathered pif1 ----------------
__global__ __launch_bounds__(256) void k_softmax2(
    const _Float16* __restrict__ y6h, const _Float16* __restrict__ pif1h,
    const int* __restrict__ idx2, const float* __restrict__ validf,
    const float* stats,
    const float* __restrict__ m3g1, const float* __restrict__ m3e1,
    float* __restrict__ out)
{
  int tid = threadIdx.x, lane = tid & 63;
  int p = blockIdx.x*4 + (tid >> 6);
  int b = p >> 12;
  int d = lane;
  float sc,sh; bn_param(stats+7*256, d, INV_R2, m3g1, m3e1, sc, sh);
  size_t rb = (size_t)p*KNn;
  float v[16]; float mx = -1e30f;
  #pragma unroll
  for (int k=0;k<16;k++){
    float t = leakyf((float)y6h[(rb+k)*64 + d]*sc + sh);
    t = (validf[rb+k] > 0.5f) ? t : -1e10f;
    v[k] = t; mx = fmaxf(mx, t);
  }
  float se = 0.f;
  #pragma unroll
  for (int k=0;k<16;k++){ float ev = __expf(v[k]-mx); v[k]=ev; se += ev; }
  float inv = 1.f/se, acc = 0.f;
  #pragma unroll
  for (int k=0;k<16;k++){
    int idx = idx2[rb+k];
    acc += v[k]*(float)pif1h[((size_t)(b*HWn) + idx)*64 + d];
  }
  out[(size_t)p*64 + d] = acc*inv;
}

// ---------------- launcher ----------------
extern "C" void kernel_launch(void* const* d_in, const int* in_sizes, int n_in,
                              void* d_out, int out_size, void* d_ws, size_t ws_size,
                              hipStream_t stream)
{
  (void)in_sizes; (void)n_in; (void)out_size; (void)ws_size;
  const float* xyz_proj      = (const float*)d_in[0];
  const float* warped_xyz    = (const float*)d_in[1];
  const float* warped_points = (const float*)d_in[2];
  const float* f2_xyz        = (const float*)d_in[4];
  const float* f2_points     = (const float*)d_in[5];
  const float* lidar_z       = (const float*)d_in[6];
  const float* m1w0=(const float*)d_in[7],  *m1g0=(const float*)d_in[9],  *m1e0=(const float*)d_in[10];
  const float* m1w1=(const float*)d_in[11], *m1g1=(const float*)d_in[13], *m1e1=(const float*)d_in[14];
  const float* piw =(const float*)d_in[15], *pib =(const float*)d_in[16], *pig =(const float*)d_in[17], *pie =(const float*)d_in[18];
  const float* m2w0=(const float*)d_in[19], *m2g0=(const float*)d_in[21], *m2e0=(const float*)d_in[22];
  const float* m2w1=(const float*)d_in[23], *m2g1=(const float*)d_in[25], *m2e1=(const float*)d_in[26];
  const float* pcw =(const float*)d_in[27], *pcb =(const float*)d_in[28], *pcg =(const float*)d_in[29], *pce =(const float*)d_in[30];
  const float* m3w0=(const float*)d_in[31], *m3g0=(const float*)d_in[33], *m3e0=(const float*)d_in[34];
  const float* m3w1=(const float*)d_in[35], *m3g1=(const float*)d_in[37], *m3e1=(const float*)d_in[38];
  float* out = (float*)d_out;

  float* ws     = (float*)d_ws;
  float* wxyz   = ws;                        // 24576
  float* normW  = wxyz   + 24576;            // 524288
  float* normF2 = normW  + 524288;           // 524288
  float* piwT   = normF2 + 524288;           // 384
  float* pcwT   = piwT   + 384;              // 640
  float* stats  = pcwT   + 640;              // 2048
  float* gram   = stats  + 2048;             // 128
  int*   idxq   = (int*)(gram + 128);        // 262144
  int*   idx2   = idxq   + 262144;           // 131072
  float* validf = (float*)(idx2 + 131072);   // 131072
  _Float16* pif1h = (_Float16*)(validf + 131072);   // 1048576 f16 = 524288 floats
  float* X1f    = validf + 131072 + 524288;
  _Float16* X1  = (_Float16*)X1f;            // 25165824 f16 = 12582912 floats
  float* y2f    = X1f + 12582912;
  _Float16* y2h = (_Float16*)y2f;            // 16777216 f16 = 8388608 floats
  float* y3f    = y2f + 8388608;
  _Float16* y3h = (_Float16*)y3f;            // 8388608 floats
  float* whb    = y3f + 8388608;             // f16 weights: 49152 f16 = 24576 floats
  _Float16* w1h = (_Float16*)whb;            // 12288
  _Float16* w2h = w1h + 12288;               // 8192
  _Float16* w3h = w2h + 8192;                // 8192
  _Float16* w4h = w3h + 8192;                // 4096
  _Float16* w5h = w4h + 4096;                // 12288
  _Float16* w6h = w5h + 12288;               // 4096
  // aliases (regions dead by the time they're overwritten):
  _Float16* y4h = (_Float16*)X1f;            // X1 dead after k_mfma_m1
  _Float16* y5h = (_Float16*)(X1f + 8388608);
  _Float16* y6h = y3h;                       // y3 dead after first k_mfma_pw64

  hipMemsetAsync(stats, 0, (2048+128)*sizeof(float), stream);
  k_prep<<<4388,256,0,stream>>>(warped_xyz, lidar_z, warped_points, f2_points,
                                m1w0, m1w1, piw, pcw, m2w0, m2w1, m3w0, m3w1,
                                wxyz, normW, normF2, piwT, pcwT,
                                w1h, w2h, w3h, w4h, w5h, w6h);
  k_knn_all<<<16384,256,0,stream>>>(warped_xyz, f2_xyz, idxq,
                                    xyz_proj, xyz_proj, idx2, validf);
  k_build_stats<<<1120,256,0,stream>>>(wxyz, f2_xyz, normW, normF2, idxq, idx2,
                                       w1h, X1, stats, gram);
  k_gram_fin<<<1,128,0,stream>>>(gram, piw, pib, pcw, pcb, stats);
  k_mfma_m1<<<1024,256,0,stream>>>(X1, w1h, w2h, m1g0, m1e0, stats, y2h);
  k_mfma_m2a<<<1024,256,0,stream>>>(wxyz, f2_xyz, idxq, piwT, pib, pig, pie,
                                    m1g1, m1e1, y2h, w3h, stats, y3h);
  k_mfma_pw64<<<1024,256,0,stream>>>(y3h, w4h, m2g0, m2e0,
                                     stats+3*256, stats+4*256, INV_R1, y4h);
  k_softmax1<<<2048,256,0,stream>>>(y2h, y4h, stats, m1g1, m1e1, m2g1, m2e1, pif1h);
  k_mfma_m3a<<<512,256,0,stream>>>(wxyz, warped_points, pif1h, idx2,
                                   pcwT, pcb, pcg, pce, w5h, stats, y5h);
  k_mfma_pw64<<<512,256,0,stream>>>(y5h, w6h, m3g0, m3e0,
                                    stats+6*256, stats+7*256, INV_R2, y6h);
  k_softmax2<<<2048,256,0,stream>>>(y6h, pif1h, idx2, validf, stats, m3g1, m3e1, out);
}